// Round 8
// baseline (208.348 us; speedup 1.0000x reference)
//
#include <hip/hip_runtime.h>
#include <hip/hip_bf16.h>

#define BB   128
#define CIN  9
#define TT   2048
#define RR   512
#define NN   (BB*RR)     // 65536
#define HID  128
#define NOUT 12

typedef __attribute__((ext_vector_type(8))) short short8;
typedef __attribute__((ext_vector_type(4))) float f32x4;

static __device__ inline unsigned short f2bf(float f) {       // RNE f32->bf16
    unsigned int u = __float_as_uint(f);
    unsigned int r = (u + 0x7fffu + ((u >> 16) & 1u)) >> 16;
    return (unsigned short)r;
}

#define MFMA16(a, b, c) __builtin_amdgcn_mfma_f32_16x16x32_bf16((a), (b), (c), 0, 0, 0)

// =======================================================================
// Fused conv1+relu+pool2 -> conv2+relu+pool2 -> nodesT bf16 [b][32][512]
// block 1024: dense-Ahat build (f32, atomics); block 1025: W1^T/W2^T bf16
// =======================================================================
__global__ __launch_bounds__(512) void k_convs(const float* __restrict__ x,
        const float* __restrict__ w1, const float* __restrict__ b1,
        const float* __restrict__ w2, const float* __restrict__ b2,
        unsigned short* __restrict__ nodesT,
        const int* __restrict__ ei, int E, int es, float* __restrict__ Af32,
        const float* __restrict__ g1w, const float* __restrict__ g2w,
        unsigned short* __restrict__ w1t, unsigned short* __restrict__ w2t) {
    __shared__ float sx[CIN][268];
    __shared__ float s1[16][132];
    __shared__ int   lcnt[512];
    __shared__ float sdisl[512];
    int tid = threadIdx.x;

    if (blockIdx.x == 1024) {
        // ---- dense normalized adjacency build ----
        float4 z = make_float4(0.f, 0.f, 0.f, 0.f);
        float4* A4 = (float4*)Af32;
        for (int i = 0; i < 128; ++i) A4[tid + i * 512] = z;   // zero 1 MB
        lcnt[tid] = 0;
        __syncthreads();                       // also drains the zero-stores
        for (int i = tid; i < es; i += 512) atomicAdd(&lcnt[ei[E + i]], 1);
        __syncthreads();
        float dv = rsqrtf((float)lcnt[tid] + 1.0f);
        sdisl[tid] = dv;
        __syncthreads();
        for (int i = tid; i < es; i += 512) {
            int row = ei[i], col = ei[E + i];
            atomicAdd(&Af32[col * 512 + row], sdisl[row] * sdisl[col]);
        }
        atomicAdd(&Af32[tid * 512 + tid], dv * dv);   // self loop
        return;
    }
    if (blockIdx.x == 1025) {
        for (int idx = tid; idx < 32 * 128; idx += 512) {
            int c = idx >> 7, f = idx & 127;
            w1t[f * 32 + c] = f2bf(g1w[idx]);
        }
        for (int idx = tid; idx < 128 * 128; idx += 512) {
            int c = idx >> 7, f = idx & 127;
            w2t[f * 128 + c] = f2bf(g2w[idx]);
        }
        return;
    }

    int b  = blockIdx.x >> 3;
    int r0 = (blockIdx.x & 7) * 64;
    int wv   = __builtin_amdgcn_readfirstlane(tid >> 6);
    int lane = tid & 63;

    for (int idx = tid; idx < CIN * 268; idx += 512) {
        int c = idx / 268, j = idx - c * 268;
        int g = 4 * r0 - 6 + j;
        float v = 0.f;
        if (g >= 0 && g < TT) v = x[(b * CIN + c) * TT + g];
        sx[c][j] = v;
    }
    __syncthreads();

#pragma unroll
    for (int cc = 0; cc < 2; ++cc) {
        int c1 = wv * 2 + cc;
        float bias1 = b1[c1];
        for (int pp = lane; pp < 132; pp += 64) {
            int p = 2 * r0 - 2 + pp;
            float val = 0.f;
            if (p >= 0 && p < 1024) {
                float a0 = bias1, a1 = bias1;
#pragma unroll
                for (int c = 0; c < CIN; ++c) {
                    const float2* px = (const float2*)&sx[c][2 * pp];
                    float2 q0 = px[0], q1 = px[1], q2 = px[2];
                    const float* wp = &w1[(c1 * CIN + c) * 5];
                    float k0 = wp[0], k1 = wp[1], k2 = wp[2], k3 = wp[3], k4 = wp[4];
                    a0 += q0.x*k0 + q0.y*k1 + q1.x*k2 + q1.y*k3 + q2.x*k4;
                    a1 += q0.y*k0 + q1.x*k1 + q1.y*k2 + q2.x*k3 + q2.y*k4;
                }
                val = fmaxf(fmaxf(a0, a1), 0.f);
            }
            s1[c1][pp] = val;
        }
    }
    __syncthreads();

    int rl = lane;
    float acc0[4], acc1[4];
#pragma unroll
    for (int o = 0; o < 4; ++o) {
        float bv = b2[wv * 4 + o];
        acc0[o] = bv; acc1[o] = bv;
    }
#pragma unroll
    for (int c = 0; c < 16; ++c) {
        const float2* ps = (const float2*)&s1[c][2 * rl];
        float2 q0 = ps[0], q1 = ps[1], q2 = ps[2];
#pragma unroll
        for (int o = 0; o < 4; ++o) {
            const float* wp = &w2[((wv * 4 + o) * 16 + c) * 5];
            float k0 = wp[0], k1 = wp[1], k2 = wp[2], k3 = wp[3], k4 = wp[4];
            acc0[o] += q0.x*k0 + q0.y*k1 + q1.x*k2 + q1.y*k3 + q2.x*k4;
            acc1[o] += q0.y*k0 + q1.x*k1 + q1.y*k2 + q2.x*k3 + q2.y*k4;
        }
    }
    // write nodesT[b][ch][node] bf16, coalesced per channel
    unsigned short* nb = nodesT + (size_t)b * 32 * 512;
    int n = r0 + rl;
    nb[(wv * 4 + 0) * 512 + n] = f2bf(fmaxf(fmaxf(acc0[0], acc1[0]), 0.f));
    nb[(wv * 4 + 1) * 512 + n] = f2bf(fmaxf(fmaxf(acc0[1], acc1[1]), 0.f));
    nb[(wv * 4 + 2) * 512 + n] = f2bf(fmaxf(fmaxf(acc0[2], acc1[2]), 0.f));
    nb[(wv * 4 + 3) * 512 + n] = f2bf(fmaxf(fmaxf(acc0[3], acc1[3]), 0.f));
}

// ---------------- Af32 -> bf16 ----------------
__global__ __launch_bounds__(256) void k_ab(const float* __restrict__ Af32,
        unsigned short* __restrict__ Ab) {
    int idx = blockIdx.x * 256 + threadIdx.x;   // 65536 float4 groups
    float4 v = ((const float4*)Af32)[idx];
    ushort4 o;
    o.x = f2bf(v.x); o.y = f2bf(v.y); o.z = f2bf(v.z); o.w = f2bf(v.w);
    ((ushort4*)Ab)[idx] = o;
}

// =======================================================================
// Layer 1: h1[64,128] = relu( (Ahat[m0:m0+64,:] @ H0[512,32]) @ W1 + b1 )
// grid 1024 = 8 mtiles x 128 samples, 256 threads (4 waves)
// =======================================================================
__global__ __launch_bounds__(256) void k_l1(const unsigned short* __restrict__ Ab,
        const unsigned short* __restrict__ nodesT, const unsigned short* __restrict__ w1t,
        const float* __restrict__ bias, unsigned short* __restrict__ h1) {
    __shared__ unsigned short sA[64][72];
    __shared__ unsigned short sB[32][72];
    __shared__ unsigned short sAgg[64][40];
    __shared__ unsigned short sW1[128][32];
    int tid = threadIdx.x;
    int vb = blockIdx.x;
    int xcd = vb & 7, slot = vb >> 3;
    int b = xcd * 16 + (slot >> 3);
    int mt = slot & 7;
    int m0 = mt * 64;

    {   // stage W1^T (1024 ushort4)
        const ushort4* src = (const ushort4*)w1t;
#pragma unroll
        for (int i = 0; i < 4; ++i) {
            int idx = tid + i * 256;
            int f = idx >> 3, c4 = idx & 7;
            *(ushort4*)&sW1[f][c4 * 4] = src[idx];
        }
    }

    int wv = tid >> 6, lane = tid & 63;
    int l15 = lane & 15, quad = lane >> 4;
    f32x4 acc0 = {0.f, 0.f, 0.f, 0.f}, acc1 = {0.f, 0.f, 0.f, 0.f};

    for (int kc = 0; kc < 8; ++kc) {
        __syncthreads();
#pragma unroll
        for (int i = 0; i < 4; ++i) {      // sA: Ahat tile 64x64
            int idx = tid + i * 256;
            int row = idx >> 4, c4 = idx & 15;
            ushort4 v = *(const ushort4*)&Ab[(size_t)(m0 + row) * 512 + kc * 64 + c4 * 4];
            *(ushort4*)&sA[row][c4 * 4] = v;
        }
#pragma unroll
        for (int i = 0; i < 2; ++i) {      // sB: nodesT chunk 32x64
            int idx = tid + i * 256;
            int nr = idx >> 4, c4 = idx & 15;
            ushort4 v = *(const ushort4*)&nodesT[((size_t)b * 32 + nr) * 512 + kc * 64 + c4 * 4];
            *(ushort4*)&sB[nr][c4 * 4] = v;
        }
        __syncthreads();
        int mw = wv * 16;
#pragma unroll
        for (int ks = 0; ks < 2; ++ks) {
            int k0 = ks * 32 + quad * 8;
            short8 a  = *(const short8*)&sA[mw + l15][k0];
            short8 b0 = *(const short8*)&sB[l15][k0];
            short8 b1 = *(const short8*)&sB[16 + l15][k0];
            acc0 = MFMA16(a, b0, acc0);
            acc1 = MFMA16(a, b1, acc1);
        }
    }
    __syncthreads();
#pragma unroll
    for (int r = 0; r < 4; ++r) {
        sAgg[wv * 16 + quad * 4 + r][l15]      = f2bf(acc0[r]);
        sAgg[wv * 16 + quad * 4 + r][16 + l15] = f2bf(acc1[r]);
    }
    __syncthreads();
    // GEMM2: sAgg[64][32] @ W1 -> +bias, relu -> h1
    short8 a2 = *(const short8*)&sAgg[wv * 16 + l15][quad * 8];
    f32x4 c2[8];
#pragma unroll
    for (int nt = 0; nt < 8; ++nt) {
        short8 bfr = *(const short8*)&sW1[nt * 16 + l15][quad * 8];
        c2[nt] = (f32x4){0.f, 0.f, 0.f, 0.f};
        c2[nt] = MFMA16(a2, bfr, c2[nt]);
    }
#pragma unroll
    for (int nt = 0; nt < 8; ++nt) {
        float bc = bias[nt * 16 + l15];
#pragma unroll
        for (int r = 0; r < 4; ++r) {
            int node = b * RR + m0 + wv * 16 + quad * 4 + r;
            h1[(size_t)node * 128 + nt * 16 + l15] = f2bf(fmaxf(c2[nt][r] + bc, 0.f));
        }
    }
}

// =======================================================================
// lin2: T = h1 @ W2, stored transposed Tt[b][128][512] bf16 (LDS transpose)
// grid 1024 = 8 mtiles x 128 samples, 256 threads
// =======================================================================
__global__ __launch_bounds__(256) void k_lin2(const unsigned short* __restrict__ h1,
        const unsigned short* __restrict__ w2t, unsigned short* __restrict__ Tt) {
    __shared__ unsigned short sH[64][136];
    __shared__ unsigned short sT[128][72];
    int tid = threadIdx.x;
    int vb = blockIdx.x;
    int xcd = vb & 7, slot = vb >> 3;
    int b = xcd * 16 + (slot >> 3);
    int mt = slot & 7;
    int m0 = mt * 64;

    {   // stage h1 rows 64x128
        const ushort4* src = (const ushort4*)(h1 + ((size_t)b * RR + m0) * 128);
#pragma unroll
        for (int i = 0; i < 8; ++i) {
            int idx = tid + i * 256;
            int row = idx >> 5, c4 = idx & 31;
            *(ushort4*)&sH[row][c4 * 4] = src[idx];
        }
    }
    __syncthreads();
    int wv = tid >> 6, lane = tid & 63;
    int l15 = lane & 15, quad = lane >> 4;
    int mw = wv * 16;
    short8 a[4];
#pragma unroll
    for (int kc = 0; kc < 4; ++kc)
        a[kc] = *(const short8*)&sH[mw + l15][kc * 32 + quad * 8];
    f32x4 acc[8];
#pragma unroll
    for (int nt = 0; nt < 8; ++nt) acc[nt] = (f32x4){0.f, 0.f, 0.f, 0.f};
#pragma unroll
    for (int kc = 0; kc < 4; ++kc)
#pragma unroll
        for (int nt = 0; nt < 8; ++nt) {
            short8 bfr = *(const short8*)&w2t[(size_t)(nt * 16 + l15) * 128 + kc * 32 + quad * 8];
            acc[nt] = MFMA16(a[kc], bfr, acc[nt]);
        }
    // transpose via LDS
#pragma unroll
    for (int nt = 0; nt < 8; ++nt)
#pragma unroll
        for (int r = 0; r < 4; ++r)
            sT[nt * 16 + l15][mw + quad * 4 + r] = f2bf(acc[nt][r]);
    __syncthreads();
#pragma unroll
    for (int i = 0; i < 8; ++i) {      // coalesced store 128x64
        int idx = tid + i * 256;
        int f = idx >> 4, c4 = idx & 15;
        ushort4 v = *(const ushort4*)&sT[f][c4 * 4];
        *(ushort4*)&Tt[((size_t)b * 128 + f) * 512 + m0 + c4 * 4] = v;
    }
}

// =======================================================================
// agg2: H2^T[128,512] = Tt[128,512] @ (B=Ahat[dst][src]) ; epilogue:
// relu(+bias) and column-sum over dst -> partial[b*2+half][128]
// grid 256 = 2 n-halves x 128 samples, 512 threads (8 waves)
// =======================================================================
__global__ __launch_bounds__(512) void k_agg2(const unsigned short* __restrict__ Ab,
        const unsigned short* __restrict__ Tt, const float* __restrict__ bias,
        float* __restrict__ partial) {
    __shared__ unsigned short sA[128][72];
    __shared__ unsigned short sB[256][72];
    int tid = threadIdx.x;
    int vb = blockIdx.x;
    int xcd = vb & 7, slot = vb >> 3;
    int b = xcd * 16 + (slot >> 1);
    int half = slot & 1;
    int n0 = half * 256;
    int wv = tid >> 6, lane = tid & 63;
    int l15 = lane & 15, quad = lane >> 4;
    f32x4 acc[16];
#pragma unroll
    for (int nt = 0; nt < 16; ++nt) acc[nt] = (f32x4){0.f, 0.f, 0.f, 0.f};

    for (int kc = 0; kc < 8; ++kc) {
        __syncthreads();
#pragma unroll
        for (int i = 0; i < 4; ++i) {      // sA: Tt chunk 128x64
            int idx = tid + i * 512;
            int f = idx >> 4, c4 = idx & 15;
            ushort4 v = *(const ushort4*)&Tt[((size_t)b * 128 + f) * 512 + kc * 64 + c4 * 4];
            *(ushort4*)&sA[f][c4 * 4] = v;
        }
#pragma unroll
        for (int i = 0; i < 8; ++i) {      // sB: Ahat chunk 256x64
            int idx = tid + i * 512;
            int nr = idx >> 4, c4 = idx & 15;
            ushort4 v = *(const ushort4*)&Ab[(size_t)(n0 + nr) * 512 + kc * 64 + c4 * 4];
            *(ushort4*)&sB[nr][c4 * 4] = v;
        }
        __syncthreads();
        int mw = wv * 16;
#pragma unroll
        for (int ks = 0; ks < 2; ++ks) {
            int k0 = ks * 32 + quad * 8;
            short8 a = *(const short8*)&sA[mw + l15][k0];
#pragma unroll
            for (int nt = 0; nt < 16; ++nt) {
                short8 bb = *(const short8*)&sB[nt * 16 + l15][k0];
                acc[nt] = MFMA16(a, bb, acc[nt]);
            }
        }
    }
    // epilogue: f = wv*16 + quad*4 + r (row), dst col = nt*16 + l15
    float brow[4];
#pragma unroll
    for (int r = 0; r < 4; ++r) brow[r] = bias[wv * 16 + quad * 4 + r];
    float colsum[4] = {0.f, 0.f, 0.f, 0.f};
#pragma unroll
    for (int nt = 0; nt < 16; ++nt)
#pragma unroll
        for (int r = 0; r < 4; ++r)
            colsum[r] += fmaxf(acc[nt][r] + brow[r], 0.f);
#pragma unroll
    for (int off = 1; off < 16; off <<= 1) {
#pragma unroll
        for (int r = 0; r < 4; ++r)
            colsum[r] += __shfl_xor(colsum[r], off, 64);
    }
    if (l15 == 0) {
#pragma unroll
        for (int r = 0; r < 4; ++r)
            partial[(size_t)(b * 2 + half) * 128 + wv * 16 + quad * 4 + r] = colsum[r];
    }
}

// ---------------- fc: combine partials -> mean -> out = mean @ fw + fb ------
__global__ __launch_bounds__(128) void k_fc(const float* __restrict__ partial,
        const float* __restrict__ fw, const float* __restrict__ fb,
        float* __restrict__ out) {
    __shared__ float sm[HID];
    int b = blockIdx.x, f = threadIdx.x;
    float acc = partial[(size_t)(b * 2) * 128 + f] + partial[(size_t)(b * 2 + 1) * 128 + f];
    sm[f] = acc * (1.0f / RR);
    __syncthreads();
    if (f < NOUT) {
        float s = fb[f];
#pragma unroll
        for (int c = 0; c < HID; ++c) s += sm[c] * fw[c * NOUT + f];
        out[b * NOUT + f] = s;
    }
}

extern "C" void kernel_launch(void* const* d_in, const int* in_sizes, int n_in,
                              void* d_out, int out_size, void* d_ws, size_t ws_size,
                              hipStream_t stream) {
    const float* x   = (const float*)d_in[0];
    const int*   ei  = (const int*)d_in[1];
    const float* c1w = (const float*)d_in[2];
    const float* c1b = (const float*)d_in[3];
    const float* c2w = (const float*)d_in[4];
    const float* c2b = (const float*)d_in[5];
    const float* g1w = (const float*)d_in[6];
    const float* g1b = (const float*)d_in[7];
    const float* g2w = (const float*)d_in[8];
    const float* g2b = (const float*)d_in[9];
    const float* fw  = (const float*)d_in[10];
    const float* fb  = (const float*)d_in[11];
    float* out = (float*)d_out;
    int E  = in_sizes[1] / 2;   // total edges (1048576)
    int es = E / BB;            // edges per sample graph (8192)

    char* ws = (char*)d_ws;
    unsigned short* nodesT = (unsigned short*)(ws);                  // 4 MB  [B][32][512]
    unsigned short* h1     = (unsigned short*)(ws + (4u  << 20));    // 16 MB [N][128]
    unsigned short* Tt     = (unsigned short*)(ws + (20u << 20));    // 16 MB [B][128][512]
    float*          Af32   = (float*)(ws + (36u << 20));             // 1 MB  [512][512]
    unsigned short* Ab     = (unsigned short*)(ws + (37u << 20));    // 0.5 MB
    unsigned short* w1t    = (unsigned short*)(ws + (38u << 20));    // 8 KB
    unsigned short* w2t    = (unsigned short*)(ws + (38u << 20) + 65536); // 32 KB
    float*          partial= (float*)(ws + (39u << 20));             // 128 KB [256][128]

    // convs (0..1023) + Ahat build (1024) + weight transpose (1025)
    k_convs<<<1026, 512, 0, stream>>>(x, c1w, c1b, c2w, c2b, nodesT,
                                      ei, E, es, Af32, g1w, g2w, w1t, w2t);
    // Ahat f32 -> bf16
    k_ab<<<256, 256, 0, stream>>>(Af32, Ab);

    // layer 1: (Ahat @ H0) @ W1 + b, relu  -> h1 bf16
    k_l1<<<1024, 256, 0, stream>>>(Ab, nodesT, w1t, g1b, h1);

    // layer 2: lin2 -> Tt ; agg GEMM + bias + relu + column-sum partials
    k_lin2<<<1024, 256, 0, stream>>>(h1, w2t, Tt);
    k_agg2<<<256, 512, 0, stream>>>(Ab, Tt, g2b, partial);

    // mean + fc
    k_fc<<<BB, 128, 0, stream>>>(partial, fw, fb, out);
}